// Round 1
// baseline (3416.828 us; speedup 1.0000x reference)
//
#include <hip/hip_runtime.h>
#include <math.h>

#define N_NODES 50000
#define N_EDGES 800000
#define ETOT    (N_EDGES + N_NODES)
#define DH      128
#define NH      4
#define NEG     0.2f
#define LN_EPS  1e-5f

// ---------- float <-> ordered uint key (for atomicMax on floats) ----------
__device__ __forceinline__ unsigned fkey(float f) {
    unsigned u = __float_as_uint(f);
    return (u & 0x80000000u) ? ~u : (u | 0x80000000u);
}
__device__ __forceinline__ float fdec(unsigned k) {
    return (k & 0x80000000u) ? __uint_as_float(k & 0x7fffffffu)
                             : __uint_as_float(~k);
}

// ---------- GEMM: Y{l,r} = X @ W{l,r} + b{l,r}, X:[n,128], W:[128,128] ----------
#define GROWS 16
__global__ __launch_bounds__(128) void gemm2_kernel(
    const float* __restrict__ X,
    const float* __restrict__ Wl, const float* __restrict__ bl,
    const float* __restrict__ Wr, const float* __restrict__ br,
    float* __restrict__ Yl, float* __restrict__ Yr)
{
    __shared__ float xs[GROWS][DH];
    const int col  = threadIdx.x;
    const int row0 = blockIdx.x * GROWS;
    for (int r = 0; r < GROWS; ++r)
        xs[r][col] = X[(size_t)(row0 + r) * DH + col];
    __syncthreads();

    float accl[GROWS], accr[GROWS];
    for (int r = 0; r < GROWS; ++r) { accl[r] = 0.f; accr[r] = 0.f; }

    for (int k = 0; k < DH; k += 4) {
        float wl0 = Wl[(k+0)*DH + col], wl1 = Wl[(k+1)*DH + col];
        float wl2 = Wl[(k+2)*DH + col], wl3 = Wl[(k+3)*DH + col];
        float wr0 = Wr[(k+0)*DH + col], wr1 = Wr[(k+1)*DH + col];
        float wr2 = Wr[(k+2)*DH + col], wr3 = Wr[(k+3)*DH + col];
        #pragma unroll
        for (int r = 0; r < GROWS; ++r) {
            float4 x4 = *(const float4*)&xs[r][k];
            accl[r] += x4.x*wl0 + x4.y*wl1 + x4.z*wl2 + x4.w*wl3;
            accr[r] += x4.x*wr0 + x4.y*wr1 + x4.z*wr2 + x4.w*wr3;
        }
    }
    const float bL = bl[col], bR = br[col];
    for (int r = 0; r < GROWS; ++r) {
        Yl[(size_t)(row0 + r) * DH + col] = accl[r] + bL;
        Yr[(size_t)(row0 + r) * DH + col] = accr[r] + bR;
    }
}

// ---------- single GEMM: Y = X @ W + b ----------
__global__ __launch_bounds__(128) void gemm1_kernel(
    const float* __restrict__ X,
    const float* __restrict__ W, const float* __restrict__ b,
    float* __restrict__ Y)
{
    __shared__ float xs[GROWS][DH];
    const int col  = threadIdx.x;
    const int row0 = blockIdx.x * GROWS;
    for (int r = 0; r < GROWS; ++r)
        xs[r][col] = X[(size_t)(row0 + r) * DH + col];
    __syncthreads();

    float acc[GROWS];
    for (int r = 0; r < GROWS; ++r) acc[r] = 0.f;

    for (int k = 0; k < DH; k += 4) {
        float w0 = W[(k+0)*DH + col], w1 = W[(k+1)*DH + col];
        float w2 = W[(k+2)*DH + col], w3 = W[(k+3)*DH + col];
        #pragma unroll
        for (int r = 0; r < GROWS; ++r) {
            float4 x4 = *(const float4*)&xs[r][k];
            acc[r] += x4.x*w0 + x4.y*w1 + x4.z*w2 + x4.w*w3;
        }
    }
    const float bb = b[col];
    for (int r = 0; r < GROWS; ++r)
        Y[(size_t)(row0 + r) * DH + col] = acc[r] + bb;
}

// ---------- edge pass 1: logits + segment max ----------
// 32 lanes per edge; lane covers channels [4*lane, 4*lane+4); head = lane>>3
__global__ __launch_bounds__(256) void edge_logits_kernel(
    const int* __restrict__ eidx,
    const float* __restrict__ xl, const float* __restrict__ xr,
    const float* __restrict__ att,
    float* __restrict__ logits, unsigned* __restrict__ lmax)
{
    const int g    = blockIdx.x * 8 + (threadIdx.x >> 5);
    const int lane = threadIdx.x & 31;
    if (g >= ETOT) return;
    int s, d;
    if (g < N_EDGES) { s = eidx[g]; d = eidx[N_EDGES + g]; }
    else             { s = d = g - N_EDGES; }

    float4 a  = *(const float4*)(xl + (size_t)s * DH + lane * 4);
    float4 bv = *(const float4*)(xr + (size_t)d * DH + lane * 4);
    float4 at = *(const float4*)(att + lane * 4);

    float m, acc = 0.f;
    m = a.x + bv.x; m = (m > 0.f) ? m : NEG * m; acc += m * at.x;
    m = a.y + bv.y; m = (m > 0.f) ? m : NEG * m; acc += m * at.y;
    m = a.z + bv.z; m = (m > 0.f) ? m : NEG * m; acc += m * at.z;
    m = a.w + bv.w; m = (m > 0.f) ? m : NEG * m; acc += m * at.w;

    acc += __shfl_xor(acc, 1);
    acc += __shfl_xor(acc, 2);
    acc += __shfl_xor(acc, 4);

    if ((lane & 7) == 0) {
        const int h = lane >> 3;
        logits[(size_t)g * NH + h] = acc;
        atomicMax(&lmax[d * NH + h], fkey(acc));
    }
}

// ---------- edge pass 2: ex = exp(l - max); den += ex; accum += xl[src]*ex ----------
__global__ __launch_bounds__(256) void edge_accum_kernel(
    const int* __restrict__ eidx,
    const float* __restrict__ xl,
    const float* __restrict__ logits, const unsigned* __restrict__ lmax,
    float* __restrict__ den, float* __restrict__ accum)
{
    const int g    = blockIdx.x * 8 + (threadIdx.x >> 5);
    const int lane = threadIdx.x & 31;
    if (g >= ETOT) return;
    int s, d;
    if (g < N_EDGES) { s = eidx[g]; d = eidx[N_EDGES + g]; }
    else             { s = d = g - N_EDGES; }

    const int h = lane >> 3;
    const float l  = logits[(size_t)g * NH + h];
    const float mx = fdec(lmax[d * NH + h]);
    const float ex = expf(l - mx);

    if ((lane & 7) == 0) atomicAdd(&den[d * NH + h], ex);

    float4 a = *(const float4*)(xl + (size_t)s * DH + lane * 4);
    float* o = accum + (size_t)d * DH + lane * 4;
    atomicAdd(o + 0, a.x * ex);
    atomicAdd(o + 1, a.y * ex);
    atomicAdd(o + 2, a.z * ex);
    atomicAdd(o + 3, a.w * ex);
}

// ---------- per-node finalize: (accum/den + bias) -> LayerNorm -> optional GELU ----------
// one 64-lane wave per node, 2 channels per lane
__global__ __launch_bounds__(256) void finalize_kernel(
    const float* __restrict__ accum, const float* __restrict__ den,
    const float* __restrict__ bias,
    const float* __restrict__ gam, const float* __restrict__ bet,
    float* __restrict__ out, int do_gelu)
{
    const int n    = blockIdx.x * 4 + (threadIdx.x >> 6);
    const int lane = threadIdx.x & 63;
    if (n >= N_NODES) return;
    const int c0 = lane * 2;

    float2 v = *(const float2*)(accum + (size_t)n * DH + c0);
    if (den != nullptr) {
        const float dn = den[n * NH + (c0 >> 5)];
        v.x = v.x / dn + bias[c0];
        v.y = v.y / dn + bias[c0 + 1];
    }

    float s  = v.x + v.y;
    float sq = v.x * v.x + v.y * v.y;
    #pragma unroll
    for (int off = 32; off; off >>= 1) {
        s  += __shfl_xor(s,  off);
        sq += __shfl_xor(sq, off);
    }
    const float mu   = s  * (1.f / 128.f);
    const float var  = sq * (1.f / 128.f) - mu * mu;
    const float rstd = rsqrtf(var + LN_EPS);

    float y0 = (v.x - mu) * rstd * gam[c0]     + bet[c0];
    float y1 = (v.y - mu) * rstd * gam[c0 + 1] + bet[c0 + 1];
    if (do_gelu) {
        y0 = 0.5f * y0 * (1.f + erff(y0 * 0.70710678118654752f));
        y1 = 0.5f * y1 * (1.f + erff(y1 * 0.70710678118654752f));
    }
    out[(size_t)n * DH + c0]     = y0;
    out[(size_t)n * DH + c0 + 1] = y1;
}

extern "C" void kernel_launch(void* const* d_in, const int* in_sizes, int n_in,
                              void* d_out, int out_size, void* d_ws, size_t ws_size,
                              hipStream_t stream)
{
    const float* x    = (const float*)d_in[0];
    const int*   eidx = (const int*)  d_in[1];

    const float* Wl[2]   = { (const float*)d_in[2],  (const float*)d_in[10] };
    const float* bl[2]   = { (const float*)d_in[3],  (const float*)d_in[11] };
    const float* Wr[2]   = { (const float*)d_in[4],  (const float*)d_in[12] };
    const float* br[2]   = { (const float*)d_in[5],  (const float*)d_in[13] };
    const float* att[2]  = { (const float*)d_in[6],  (const float*)d_in[14] };
    const float* bias[2] = { (const float*)d_in[7],  (const float*)d_in[15] };
    const float* gam[2]  = { (const float*)d_in[8],  (const float*)d_in[16] };
    const float* bet[2]  = { (const float*)d_in[9],  (const float*)d_in[17] };
    const float* Wout    = (const float*)d_in[18];
    const float* bout    = (const float*)d_in[19];
    const float* gout    = (const float*)d_in[20];
    const float* boutln  = (const float*)d_in[21];

    float* out = (float*)d_out;

    const size_t NF = (size_t)N_NODES * DH;   // 6.4M floats
    float*    xl     = (float*)d_ws;
    float*    xr     = xl + NF;
    float*    accum  = xr + NF;
    float*    h1     = accum + NF;
    float*    h2     = h1 + NF;
    float*    logits = h2 + NF;
    unsigned* lmax   = (unsigned*)(logits + (size_t)ETOT * NH);
    float*    den    = (float*)(lmax + (size_t)N_NODES * NH);

    const int gemmBlocks = N_NODES / GROWS;      // 3125
    const int edgeBlocks = (ETOT + 7) / 8;       // 106250
    const int nodeBlocks = N_NODES / 4;          // 12500

    const float* hin = x;
    float* hout[2] = { h1, h2 };

    for (int L = 0; L < 2; ++L) {
        gemm2_kernel<<<gemmBlocks, 128, 0, stream>>>(hin, Wl[L], bl[L], Wr[L], br[L], xl, xr);
        hipMemsetAsync(lmax,  0, (size_t)N_NODES * NH * sizeof(unsigned), stream);
        hipMemsetAsync(den,   0, (size_t)N_NODES * NH * sizeof(float),    stream);
        hipMemsetAsync(accum, 0, NF * sizeof(float),                      stream);
        edge_logits_kernel<<<edgeBlocks, 256, 0, stream>>>(eidx, xl, xr, att[L], logits, lmax);
        edge_accum_kernel <<<edgeBlocks, 256, 0, stream>>>(eidx, xl, logits, lmax, den, accum);
        finalize_kernel   <<<nodeBlocks, 256, 0, stream>>>(accum, den, bias[L], gam[L], bet[L], hout[L], 1);
        hin = hout[L];
    }

    // output projection + final LayerNorm
    gemm1_kernel   <<<gemmBlocks, 128, 0, stream>>>(h2, Wout, bout, xl);
    finalize_kernel<<<nodeBlocks, 256, 0, stream>>>(xl, nullptr, nullptr, gout, boutln, out, 0);
}

// Round 2
// 660.119 us; speedup vs baseline: 5.1761x; 5.1761x over previous
//
#include <hip/hip_runtime.h>
#include <math.h>

#define N_NODES 50000
#define N_EDGES 800000
#define ETOT    (N_EDGES + N_NODES)
#define DH      128
#define NH      4
#define NEG     0.2f
#define LN_EPS  1e-5f

// ============================== GEMMs ==============================
#define GROWS 16
__global__ __launch_bounds__(128) void gemm2_kernel(
    const float* __restrict__ X,
    const float* __restrict__ Wl, const float* __restrict__ bl,
    const float* __restrict__ Wr, const float* __restrict__ br,
    float* __restrict__ Yl, float* __restrict__ Yr)
{
    __shared__ float xs[GROWS][DH];
    const int col  = threadIdx.x;
    const int row0 = blockIdx.x * GROWS;
    for (int r = 0; r < GROWS; ++r)
        xs[r][col] = X[(size_t)(row0 + r) * DH + col];
    __syncthreads();

    float accl[GROWS], accr[GROWS];
    for (int r = 0; r < GROWS; ++r) { accl[r] = 0.f; accr[r] = 0.f; }

    for (int k = 0; k < DH; k += 4) {
        float wl0 = Wl[(k+0)*DH + col], wl1 = Wl[(k+1)*DH + col];
        float wl2 = Wl[(k+2)*DH + col], wl3 = Wl[(k+3)*DH + col];
        float wr0 = Wr[(k+0)*DH + col], wr1 = Wr[(k+1)*DH + col];
        float wr2 = Wr[(k+2)*DH + col], wr3 = Wr[(k+3)*DH + col];
        #pragma unroll
        for (int r = 0; r < GROWS; ++r) {
            float4 x4 = *(const float4*)&xs[r][k];
            accl[r] += x4.x*wl0 + x4.y*wl1 + x4.z*wl2 + x4.w*wl3;
            accr[r] += x4.x*wr0 + x4.y*wr1 + x4.z*wr2 + x4.w*wr3;
        }
    }
    const float bL = bl[col], bR = br[col];
    for (int r = 0; r < GROWS; ++r) {
        Yl[(size_t)(row0 + r) * DH + col] = accl[r] + bL;
        Yr[(size_t)(row0 + r) * DH + col] = accr[r] + bR;
    }
}

__global__ __launch_bounds__(128) void gemm1_kernel(
    const float* __restrict__ X,
    const float* __restrict__ W, const float* __restrict__ b,
    float* __restrict__ Y)
{
    __shared__ float xs[GROWS][DH];
    const int col  = threadIdx.x;
    const int row0 = blockIdx.x * GROWS;
    for (int r = 0; r < GROWS; ++r)
        xs[r][col] = X[(size_t)(row0 + r) * DH + col];
    __syncthreads();

    float acc[GROWS];
    for (int r = 0; r < GROWS; ++r) acc[r] = 0.f;

    for (int k = 0; k < DH; k += 4) {
        float w0 = W[(k+0)*DH + col], w1 = W[(k+1)*DH + col];
        float w2 = W[(k+2)*DH + col], w3 = W[(k+3)*DH + col];
        #pragma unroll
        for (int r = 0; r < GROWS; ++r) {
            float4 x4 = *(const float4*)&xs[r][k];
            acc[r] += x4.x*w0 + x4.y*w1 + x4.z*w2 + x4.w*w3;
        }
    }
    const float bb = b[col];
    for (int r = 0; r < GROWS; ++r)
        Y[(size_t)(row0 + r) * DH + col] = acc[r] + bb;
}

// ========================= CSR construction =========================
__global__ __launch_bounds__(256) void degree_kernel(
    const int* __restrict__ eidx, int* __restrict__ deg)
{
    const int i = blockIdx.x * 256 + threadIdx.x;
    if (i >= ETOT) return;
    const int d = (i < N_EDGES) ? eidx[N_EDGES + i] : (i - N_EDGES);
    atomicAdd(&deg[d], 1);
}

#define SCAN_T 1024
#define SCAN_NPT ((N_NODES + SCAN_T - 1) / SCAN_T)   // 49
__global__ __launch_bounds__(SCAN_T) void scan_kernel(
    const int* __restrict__ deg,
    int* __restrict__ rowptr, int* __restrict__ cursor)
{
    __shared__ int buf[2][SCAN_T];
    const int t = threadIdx.x;
    const int base = t * SCAN_NPT;
    int sum = 0;
    for (int i = 0; i < SCAN_NPT; ++i) {
        const int idx = base + i;
        if (idx < N_NODES) sum += deg[idx];
    }
    buf[0][t] = sum;
    __syncthreads();
    int pi = 0;
    for (int off = 1; off < SCAN_T; off <<= 1) {
        int v = buf[pi][t];
        if (t >= off) v += buf[pi][t - off];
        buf[pi ^ 1][t] = v;
        __syncthreads();
        pi ^= 1;
    }
    int run = buf[pi][t] - sum;   // exclusive prefix
    for (int i = 0; i < SCAN_NPT; ++i) {
        const int idx = base + i;
        if (idx < N_NODES) {
            rowptr[idx] = run;
            cursor[idx] = run;
            run += deg[idx];
        }
    }
}

__global__ __launch_bounds__(256) void scatter_kernel(
    const int* __restrict__ eidx, int* __restrict__ cursor,
    int* __restrict__ csr_src)
{
    const int i = blockIdx.x * 256 + threadIdx.x;
    if (i >= ETOT) return;
    int s, d;
    if (i < N_EDGES) { s = eidx[i]; d = eidx[N_EDGES + i]; }
    else             { s = d = i - N_EDGES; }
    const int slot = atomicAdd(&cursor[d], 1);
    csr_src[slot] = s;
}

// ====== fused per-node GAT: online softmax + bias + LN + GELU ======
// one 64-lane wave per destination node; lane handles channels 2*lane, 2*lane+1
__global__ __launch_bounds__(256) void gat_node_kernel(
    const int* __restrict__ rowptr, const int* __restrict__ deg,
    const int* __restrict__ csr_src,
    const float* __restrict__ xl, const float* __restrict__ xr,
    const float* __restrict__ att, const float* __restrict__ bias,
    const float* __restrict__ gam, const float* __restrict__ bet,
    float* __restrict__ out)
{
    const int n    = blockIdx.x * 4 + (threadIdx.x >> 6);
    const int lane = threadIdx.x & 63;
    if (n >= N_NODES) return;
    const int c0 = lane * 2;

    const float2 xrv = *(const float2*)(xr + (size_t)n * DH + c0);
    const float2 atv = *(const float2*)(att + c0);

    float m = -INFINITY, den = 0.f, a0 = 0.f, a1 = 0.f;
    const int beg = rowptr[n];
    const int end = beg + deg[n];

    for (int e = beg; e < end; ++e) {
        const int s = csr_src[e];
        const float2 xv = *(const float2*)(xl + (size_t)s * DH + c0);
        float m0 = xv.x + xrv.x; m0 = (m0 > 0.f) ? m0 : NEG * m0;
        float m1 = xv.y + xrv.y; m1 = (m1 > 0.f) ? m1 : NEG * m1;
        float l = m0 * atv.x + m1 * atv.y;
        // reduce over the 16 lanes of this head (32 channels)
        l += __shfl_xor(l, 1);
        l += __shfl_xor(l, 2);
        l += __shfl_xor(l, 4);
        l += __shfl_xor(l, 8);
        const float nm = fmaxf(m, l);
        const float sc = __expf(m - nm);
        const float w  = __expf(l - nm);
        den = den * sc + w;
        a0  = a0  * sc + xv.x * w;
        a1  = a1  * sc + xv.y * w;
        m = nm;
    }

    const float inv = 1.f / den;
    float v0 = a0 * inv + bias[c0];
    float v1 = a1 * inv + bias[c0 + 1];

    // LayerNorm over 128 channels (64 lanes x 2)
    float s2 = v0 + v1, sq = v0 * v0 + v1 * v1;
    #pragma unroll
    for (int off = 32; off; off >>= 1) {
        s2 += __shfl_xor(s2, off);
        sq += __shfl_xor(sq, off);
    }
    const float mu   = s2 * (1.f / 128.f);
    const float var  = sq * (1.f / 128.f) - mu * mu;
    const float rstd = rsqrtf(var + LN_EPS);

    float y0 = (v0 - mu) * rstd * gam[c0]     + bet[c0];
    float y1 = (v1 - mu) * rstd * gam[c0 + 1] + bet[c0 + 1];
    // exact GELU
    y0 = 0.5f * y0 * (1.f + erff(y0 * 0.70710678118654752f));
    y1 = 0.5f * y1 * (1.f + erff(y1 * 0.70710678118654752f));

    out[(size_t)n * DH + c0]     = y0;
    out[(size_t)n * DH + c0 + 1] = y1;
}

// ---------- final LayerNorm (no GELU, no softmax) ----------
__global__ __launch_bounds__(256) void finalize_kernel(
    const float* __restrict__ v_in,
    const float* __restrict__ gam, const float* __restrict__ bet,
    float* __restrict__ out)
{
    const int n    = blockIdx.x * 4 + (threadIdx.x >> 6);
    const int lane = threadIdx.x & 63;
    if (n >= N_NODES) return;
    const int c0 = lane * 2;

    float2 v = *(const float2*)(v_in + (size_t)n * DH + c0);
    float s  = v.x + v.y;
    float sq = v.x * v.x + v.y * v.y;
    #pragma unroll
    for (int off = 32; off; off >>= 1) {
        s  += __shfl_xor(s,  off);
        sq += __shfl_xor(sq, off);
    }
    const float mu   = s  * (1.f / 128.f);
    const float var  = sq * (1.f / 128.f) - mu * mu;
    const float rstd = rsqrtf(var + LN_EPS);

    out[(size_t)n * DH + c0]     = (v.x - mu) * rstd * gam[c0]     + bet[c0];
    out[(size_t)n * DH + c0 + 1] = (v.y - mu) * rstd * gam[c0 + 1] + bet[c0 + 1];
}

extern "C" void kernel_launch(void* const* d_in, const int* in_sizes, int n_in,
                              void* d_out, int out_size, void* d_ws, size_t ws_size,
                              hipStream_t stream)
{
    const float* x    = (const float*)d_in[0];
    const int*   eidx = (const int*)  d_in[1];

    const float* Wl[2]   = { (const float*)d_in[2],  (const float*)d_in[10] };
    const float* bl[2]   = { (const float*)d_in[3],  (const float*)d_in[11] };
    const float* Wr[2]   = { (const float*)d_in[4],  (const float*)d_in[12] };
    const float* br[2]   = { (const float*)d_in[5],  (const float*)d_in[13] };
    const float* att[2]  = { (const float*)d_in[6],  (const float*)d_in[14] };
    const float* bias[2] = { (const float*)d_in[7],  (const float*)d_in[15] };
    const float* gam[2]  = { (const float*)d_in[8],  (const float*)d_in[16] };
    const float* bet[2]  = { (const float*)d_in[9],  (const float*)d_in[17] };
    const float* Wout    = (const float*)d_in[18];
    const float* bout    = (const float*)d_in[19];
    const float* gout    = (const float*)d_in[20];
    const float* boutln  = (const float*)d_in[21];

    float* out = (float*)d_out;

    const size_t NF = (size_t)N_NODES * DH;
    float* xl      = (float*)d_ws;
    float* xr      = xl + NF;
    float* h1      = xr + NF;
    float* h2      = h1 + NF;
    int*   csr_src = (int*)(h2 + NF);
    int*   deg     = csr_src + ETOT;
    int*   rowptr  = deg + N_NODES;
    int*   cursor  = rowptr + N_NODES;

    const int gemmBlocks = N_NODES / GROWS;      // 3125
    const int etBlocks   = (ETOT + 255) / 256;
    const int nodeBlocks = N_NODES / 4;          // 12500

    // ---- CSR (identical for both layers; rebuilt every call) ----
    hipMemsetAsync(deg, 0, N_NODES * sizeof(int), stream);
    degree_kernel <<<etBlocks, 256, 0, stream>>>(eidx, deg);
    scan_kernel   <<<1, SCAN_T, 0, stream>>>(deg, rowptr, cursor);
    scatter_kernel<<<etBlocks, 256, 0, stream>>>(eidx, cursor, csr_src);

    // ---- layer 0 ----
    gemm2_kernel   <<<gemmBlocks, 128, 0, stream>>>(x, Wl[0], bl[0], Wr[0], br[0], xl, xr);
    gat_node_kernel<<<nodeBlocks, 256, 0, stream>>>(rowptr, deg, csr_src, xl, xr,
                                                    att[0], bias[0], gam[0], bet[0], h1);
    // ---- layer 1 ----
    gemm2_kernel   <<<gemmBlocks, 128, 0, stream>>>(h1, Wl[1], bl[1], Wr[1], br[1], xl, xr);
    gat_node_kernel<<<nodeBlocks, 256, 0, stream>>>(rowptr, deg, csr_src, xl, xr,
                                                    att[1], bias[1], gam[1], bet[1], h2);

    // ---- output projection + final LayerNorm ----
    gemm1_kernel   <<<gemmBlocks, 128, 0, stream>>>(h2, Wout, bout, xl);
    finalize_kernel<<<nodeBlocks, 256, 0, stream>>>(xl, gout, boutln, out);
}

// Round 3
// 454.156 us; speedup vs baseline: 7.5235x; 1.4535x over previous
//
#include <hip/hip_runtime.h>
#include <math.h>

#define N_NODES 50000
#define N_EDGES 800000
#define ETOT    (N_EDGES + N_NODES)
#define DH      128
#define NH      4
#define NEG     0.2f
#define LN_EPS  1e-5f
#define NBLK    ((N_NODES + 255) / 256)   // 196 scan blocks

// ============================== GEMMs ==============================
#define GROWS 16
__global__ __launch_bounds__(128) void gemm2_kernel(
    const float* __restrict__ X,
    const float* __restrict__ Wl, const float* __restrict__ bl,
    const float* __restrict__ Wr, const float* __restrict__ br,
    float* __restrict__ Yl, float* __restrict__ Yr)
{
    __shared__ float xs[GROWS][DH];
    const int col  = threadIdx.x;
    const int row0 = blockIdx.x * GROWS;
    for (int r = 0; r < GROWS; ++r)
        xs[r][col] = X[(size_t)(row0 + r) * DH + col];
    __syncthreads();

    float accl[GROWS], accr[GROWS];
    for (int r = 0; r < GROWS; ++r) { accl[r] = 0.f; accr[r] = 0.f; }

    for (int k = 0; k < DH; k += 4) {
        float wl0 = Wl[(k+0)*DH + col], wl1 = Wl[(k+1)*DH + col];
        float wl2 = Wl[(k+2)*DH + col], wl3 = Wl[(k+3)*DH + col];
        float wr0 = Wr[(k+0)*DH + col], wr1 = Wr[(k+1)*DH + col];
        float wr2 = Wr[(k+2)*DH + col], wr3 = Wr[(k+3)*DH + col];
        #pragma unroll
        for (int r = 0; r < GROWS; ++r) {
            float4 x4 = *(const float4*)&xs[r][k];
            accl[r] += x4.x*wl0 + x4.y*wl1 + x4.z*wl2 + x4.w*wl3;
            accr[r] += x4.x*wr0 + x4.y*wr1 + x4.z*wr2 + x4.w*wr3;
        }
    }
    const float bL = bl[col], bR = br[col];
    for (int r = 0; r < GROWS; ++r) {
        Yl[(size_t)(row0 + r) * DH + col] = accl[r] + bL;
        Yr[(size_t)(row0 + r) * DH + col] = accr[r] + bR;
    }
}

__global__ __launch_bounds__(128) void gemm1_kernel(
    const float* __restrict__ X,
    const float* __restrict__ W, const float* __restrict__ b,
    float* __restrict__ Y)
{
    __shared__ float xs[GROWS][DH];
    const int col  = threadIdx.x;
    const int row0 = blockIdx.x * GROWS;
    for (int r = 0; r < GROWS; ++r)
        xs[r][col] = X[(size_t)(row0 + r) * DH + col];
    __syncthreads();

    float acc[GROWS];
    for (int r = 0; r < GROWS; ++r) acc[r] = 0.f;

    for (int k = 0; k < DH; k += 4) {
        float w0 = W[(k+0)*DH + col], w1 = W[(k+1)*DH + col];
        float w2 = W[(k+2)*DH + col], w3 = W[(k+3)*DH + col];
        #pragma unroll
        for (int r = 0; r < GROWS; ++r) {
            float4 x4 = *(const float4*)&xs[r][k];
            acc[r] += x4.x*w0 + x4.y*w1 + x4.z*w2 + x4.w*w3;
        }
    }
    const float bb = b[col];
    for (int r = 0; r < GROWS; ++r)
        Y[(size_t)(row0 + r) * DH + col] = acc[r] + bb;
}

// ========================= CSR construction =========================
__global__ __launch_bounds__(256) void degree_kernel(
    const int* __restrict__ eidx, int* __restrict__ deg)
{
    const int i = blockIdx.x * 256 + threadIdx.x;
    if (i >= ETOT) return;
    const int d = (i < N_EDGES) ? eidx[N_EDGES + i] : (i - N_EDGES);
    atomicAdd(&deg[d], 1);
}

// stage 1: per-block (256 nodes) degree sums
__global__ __launch_bounds__(256) void block_sum_kernel(
    const int* __restrict__ deg, int* __restrict__ bsum)
{
    const int i    = blockIdx.x * 256 + threadIdx.x;
    const int lane = threadIdx.x & 63;
    const int wid  = threadIdx.x >> 6;
    int v = (i < N_NODES) ? deg[i] : 0;
    #pragma unroll
    for (int off = 32; off; off >>= 1) v += __shfl_xor(v, off);
    __shared__ int ws[4];
    if (lane == 0) ws[wid] = v;
    __syncthreads();
    if (threadIdx.x == 0) bsum[blockIdx.x] = ws[0] + ws[1] + ws[2] + ws[3];
}

// stage 2: exclusive scan of the 196 block sums (single block)
__global__ __launch_bounds__(256) void scan_partials_kernel(
    const int* __restrict__ bsum, int* __restrict__ boff)
{
    const int t    = threadIdx.x;
    const int lane = t & 63;
    const int wid  = t >> 6;
    int v = (t < NBLK) ? bsum[t] : 0;
    int inc = v;
    #pragma unroll
    for (int off = 1; off < 64; off <<= 1) {
        int u = __shfl_up(inc, off);
        if (lane >= off) inc += u;
    }
    __shared__ int ws[4];
    if (lane == 63) ws[wid] = inc;
    __syncthreads();
    int add = 0;
    for (int w = 0; w < wid; ++w) add += ws[w];
    if (t < NBLK) boff[t] = add + inc - v;
}

// stage 3: per-node exclusive prefix -> rowptr, cursor
__global__ __launch_bounds__(256) void rowptr_kernel(
    const int* __restrict__ deg, const int* __restrict__ boff,
    int* __restrict__ rowptr, int* __restrict__ cursor)
{
    const int i    = blockIdx.x * 256 + threadIdx.x;
    const int lane = threadIdx.x & 63;
    const int wid  = threadIdx.x >> 6;
    int v = (i < N_NODES) ? deg[i] : 0;
    int inc = v;
    #pragma unroll
    for (int off = 1; off < 64; off <<= 1) {
        int u = __shfl_up(inc, off);
        if (lane >= off) inc += u;
    }
    __shared__ int ws[4];
    if (lane == 63) ws[wid] = inc;
    __syncthreads();
    int add = boff[blockIdx.x];
    for (int w = 0; w < wid; ++w) add += ws[w];
    if (i < N_NODES) {
        const int ex = add + inc - v;
        rowptr[i] = ex;
        cursor[i] = ex;
    }
}

__global__ __launch_bounds__(256) void scatter_kernel(
    const int* __restrict__ eidx, int* __restrict__ cursor,
    int* __restrict__ csr_src)
{
    const int i = blockIdx.x * 256 + threadIdx.x;
    if (i >= ETOT) return;
    int s, d;
    if (i < N_EDGES) { s = eidx[i]; d = eidx[N_EDGES + i]; }
    else             { s = d = i - N_EDGES; }
    const int slot = atomicAdd(&cursor[d], 1);
    csr_src[slot] = s;
}

// ====== fused per-node GAT: 4-way ILP online softmax + bias + LN + GELU ======
// one 64-lane wave per destination node; lane handles channels 2*lane, 2*lane+1
__global__ __launch_bounds__(256) void gat_node_kernel(
    const int* __restrict__ rowptr, const int* __restrict__ deg,
    const int* __restrict__ csr_src,
    const float* __restrict__ xl, const float* __restrict__ xr,
    const float* __restrict__ att, const float* __restrict__ bias,
    const float* __restrict__ gam, const float* __restrict__ bet,
    float* __restrict__ out)
{
    const int n    = blockIdx.x * 4 + (threadIdx.x >> 6);
    const int lane = threadIdx.x & 63;
    if (n >= N_NODES) return;
    const int c0 = lane * 2;

    const float2 xrv = *(const float2*)(xr + (size_t)n * DH + c0);
    const float2 atv = *(const float2*)(att + c0);

    // 4 independent online-softmax states
    float m0 = -INFINITY, m1 = -INFINITY, m2 = -INFINITY, m3 = -INFINITY;
    float d0 = 0.f, d1 = 0.f, d2 = 0.f, d3 = 0.f;
    float p0x = 0.f, p0y = 0.f, p1x = 0.f, p1y = 0.f;
    float p2x = 0.f, p2y = 0.f, p3x = 0.f, p3y = 0.f;

    const int beg = rowptr[n];
    const int end = beg + deg[n];
    int e = beg;

    for (; e + 4 <= end; e += 4) {
        const int s0 = csr_src[e], s1 = csr_src[e+1];
        const int s2 = csr_src[e+2], s3 = csr_src[e+3];
        const float2 x0 = *(const float2*)(xl + (size_t)s0 * DH + c0);
        const float2 x1 = *(const float2*)(xl + (size_t)s1 * DH + c0);
        const float2 x2 = *(const float2*)(xl + (size_t)s2 * DH + c0);
        const float2 x3 = *(const float2*)(xl + (size_t)s3 * DH + c0);

        float t, l0, l1, l2, l3;
        t = x0.x + xrv.x; t = (t > 0.f) ? t : NEG * t; l0  = t * atv.x;
        t = x0.y + xrv.y; t = (t > 0.f) ? t : NEG * t; l0 += t * atv.y;
        t = x1.x + xrv.x; t = (t > 0.f) ? t : NEG * t; l1  = t * atv.x;
        t = x1.y + xrv.y; t = (t > 0.f) ? t : NEG * t; l1 += t * atv.y;
        t = x2.x + xrv.x; t = (t > 0.f) ? t : NEG * t; l2  = t * atv.x;
        t = x2.y + xrv.y; t = (t > 0.f) ? t : NEG * t; l2 += t * atv.y;
        t = x3.x + xrv.x; t = (t > 0.f) ? t : NEG * t; l3  = t * atv.x;
        t = x3.y + xrv.y; t = (t > 0.f) ? t : NEG * t; l3 += t * atv.y;

        // per-head (16-lane) reduction, 4 chains interleaved for ILP
        l0 += __shfl_xor(l0, 1);  l1 += __shfl_xor(l1, 1);
        l2 += __shfl_xor(l2, 1);  l3 += __shfl_xor(l3, 1);
        l0 += __shfl_xor(l0, 2);  l1 += __shfl_xor(l1, 2);
        l2 += __shfl_xor(l2, 2);  l3 += __shfl_xor(l3, 2);
        l0 += __shfl_xor(l0, 4);  l1 += __shfl_xor(l1, 4);
        l2 += __shfl_xor(l2, 4);  l3 += __shfl_xor(l3, 4);
        l0 += __shfl_xor(l0, 8);  l1 += __shfl_xor(l1, 8);
        l2 += __shfl_xor(l2, 8);  l3 += __shfl_xor(l3, 8);

        float nm, sc, w;
        nm = fmaxf(m0, l0); sc = __expf(m0 - nm); w = __expf(l0 - nm);
        d0 = d0 * sc + w; p0x = p0x * sc + x0.x * w; p0y = p0y * sc + x0.y * w; m0 = nm;
        nm = fmaxf(m1, l1); sc = __expf(m1 - nm); w = __expf(l1 - nm);
        d1 = d1 * sc + w; p1x = p1x * sc + x1.x * w; p1y = p1y * sc + x1.y * w; m1 = nm;
        nm = fmaxf(m2, l2); sc = __expf(m2 - nm); w = __expf(l2 - nm);
        d2 = d2 * sc + w; p2x = p2x * sc + x2.x * w; p2y = p2y * sc + x2.y * w; m2 = nm;
        nm = fmaxf(m3, l3); sc = __expf(m3 - nm); w = __expf(l3 - nm);
        d3 = d3 * sc + w; p3x = p3x * sc + x3.x * w; p3y = p3y * sc + x3.y * w; m3 = nm;
    }
    // tail (0-3 edges) -> state 0
    for (; e < end; ++e) {
        const int s = csr_src[e];
        const float2 xv = *(const float2*)(xl + (size_t)s * DH + c0);
        float t, l;
        t = xv.x + xrv.x; t = (t > 0.f) ? t : NEG * t; l  = t * atv.x;
        t = xv.y + xrv.y; t = (t > 0.f) ? t : NEG * t; l += t * atv.y;
        l += __shfl_xor(l, 1);
        l += __shfl_xor(l, 2);
        l += __shfl_xor(l, 4);
        l += __shfl_xor(l, 8);
        const float nm = fmaxf(m0, l);
        const float sc = __expf(m0 - nm);
        const float w  = __expf(l - nm);
        d0 = d0 * sc + w; p0x = p0x * sc + xv.x * w; p0y = p0y * sc + xv.y * w; m0 = nm;
    }

    // merge the 4 states
    const float M = fmaxf(fmaxf(m0, m1), fmaxf(m2, m3));
    const float e0 = __expf(m0 - M), e1 = __expf(m1 - M);
    const float e2 = __expf(m2 - M), e3 = __expf(m3 - M);
    const float den = d0*e0 + d1*e1 + d2*e2 + d3*e3;
    const float ax  = p0x*e0 + p1x*e1 + p2x*e2 + p3x*e3;
    const float ay  = p0y*e0 + p1y*e1 + p2y*e2 + p3y*e3;

    const float inv = 1.f / den;
    float v0 = ax * inv + bias[c0];
    float v1 = ay * inv + bias[c0 + 1];

    // LayerNorm over 128 channels (64 lanes x 2)
    float s2 = v0 + v1, sq = v0 * v0 + v1 * v1;
    #pragma unroll
    for (int off = 32; off; off >>= 1) {
        s2 += __shfl_xor(s2, off);
        sq += __shfl_xor(sq, off);
    }
    const float mu   = s2 * (1.f / 128.f);
    const float var  = sq * (1.f / 128.f) - mu * mu;
    const float rstd = rsqrtf(var + LN_EPS);

    float y0 = (v0 - mu) * rstd * gam[c0]     + bet[c0];
    float y1 = (v1 - mu) * rstd * gam[c0 + 1] + bet[c0 + 1];
    y0 = 0.5f * y0 * (1.f + erff(y0 * 0.70710678118654752f));
    y1 = 0.5f * y1 * (1.f + erff(y1 * 0.70710678118654752f));

    out[(size_t)n * DH + c0]     = y0;
    out[(size_t)n * DH + c0 + 1] = y1;
}

// ---------- final LayerNorm (no GELU, no softmax) ----------
__global__ __launch_bounds__(256) void finalize_kernel(
    const float* __restrict__ v_in,
    const float* __restrict__ gam, const float* __restrict__ bet,
    float* __restrict__ out)
{
    const int n    = blockIdx.x * 4 + (threadIdx.x >> 6);
    const int lane = threadIdx.x & 63;
    if (n >= N_NODES) return;
    const int c0 = lane * 2;

    float2 v = *(const float2*)(v_in + (size_t)n * DH + c0);
    float s  = v.x + v.y;
    float sq = v.x * v.x + v.y * v.y;
    #pragma unroll
    for (int off = 32; off; off >>= 1) {
        s  += __shfl_xor(s,  off);
        sq += __shfl_xor(sq, off);
    }
    const float mu   = s  * (1.f / 128.f);
    const float var  = sq * (1.f / 128.f) - mu * mu;
    const float rstd = rsqrtf(var + LN_EPS);

    out[(size_t)n * DH + c0]     = (v.x - mu) * rstd * gam[c0]     + bet[c0];
    out[(size_t)n * DH + c0 + 1] = (v.y - mu) * rstd * gam[c0 + 1] + bet[c0 + 1];
}

extern "C" void kernel_launch(void* const* d_in, const int* in_sizes, int n_in,
                              void* d_out, int out_size, void* d_ws, size_t ws_size,
                              hipStream_t stream)
{
    const float* x    = (const float*)d_in[0];
    const int*   eidx = (const int*)  d_in[1];

    const float* Wl[2]   = { (const float*)d_in[2],  (const float*)d_in[10] };
    const float* bl[2]   = { (const float*)d_in[3],  (const float*)d_in[11] };
    const float* Wr[2]   = { (const float*)d_in[4],  (const float*)d_in[12] };
    const float* br[2]   = { (const float*)d_in[5],  (const float*)d_in[13] };
    const float* att[2]  = { (const float*)d_in[6],  (const float*)d_in[14] };
    const float* bias[2] = { (const float*)d_in[7],  (const float*)d_in[15] };
    const float* gam[2]  = { (const float*)d_in[8],  (const float*)d_in[16] };
    const float* bet[2]  = { (const float*)d_in[9],  (const float*)d_in[17] };
    const float* Wout    = (const float*)d_in[18];
    const float* bout    = (const float*)d_in[19];
    const float* gout    = (const float*)d_in[20];
    const float* boutln  = (const float*)d_in[21];

    float* out = (float*)d_out;

    const size_t NF = (size_t)N_NODES * DH;
    float* xl      = (float*)d_ws;
    float* xr      = xl + NF;
    float* h1      = xr + NF;
    float* h2      = h1 + NF;
    int*   csr_src = (int*)(h2 + NF);
    int*   deg     = csr_src + ETOT;
    int*   rowptr  = deg + N_NODES;
    int*   cursor  = rowptr + N_NODES;
    int*   bsum    = cursor + N_NODES;
    int*   boff    = bsum + NBLK;

    const int gemmBlocks = N_NODES / GROWS;      // 3125
    const int etBlocks   = (ETOT + 255) / 256;
    const int nodeBlocks = N_NODES / 4;          // 12500

    // ---- CSR (deterministic rebuild every call) ----
    hipMemsetAsync(deg, 0, N_NODES * sizeof(int), stream);
    degree_kernel      <<<etBlocks, 256, 0, stream>>>(eidx, deg);
    block_sum_kernel   <<<NBLK, 256, 0, stream>>>(deg, bsum);
    scan_partials_kernel<<<1, 256, 0, stream>>>(bsum, boff);
    rowptr_kernel      <<<NBLK, 256, 0, stream>>>(deg, boff, rowptr, cursor);
    scatter_kernel     <<<etBlocks, 256, 0, stream>>>(eidx, cursor, csr_src);

    // ---- layer 0 ----
    gemm2_kernel   <<<gemmBlocks, 128, 0, stream>>>(x, Wl[0], bl[0], Wr[0], br[0], xl, xr);
    gat_node_kernel<<<nodeBlocks, 256, 0, stream>>>(rowptr, deg, csr_src, xl, xr,
                                                    att[0], bias[0], gam[0], bet[0], h1);
    // ---- layer 1 ----
    gemm2_kernel   <<<gemmBlocks, 128, 0, stream>>>(h1, Wl[1], bl[1], Wr[1], br[1], xl, xr);
    gat_node_kernel<<<nodeBlocks, 256, 0, stream>>>(rowptr, deg, csr_src, xl, xr,
                                                    att[1], bias[1], gam[1], bet[1], h2);

    // ---- output projection + final LayerNorm ----
    gemm1_kernel   <<<gemmBlocks, 128, 0, stream>>>(h2, Wout, bout, xl);
    finalize_kernel<<<nodeBlocks, 256, 0, stream>>>(xl, gout, boutln, out);
}

// Round 4
// 354.296 us; speedup vs baseline: 9.6440x; 1.2819x over previous
//
#include <hip/hip_runtime.h>
#include <math.h>

#define N_NODES 50000
#define N_EDGES 800000
#define ETOT    (N_EDGES + N_NODES)
#define DH      128
#define NH      4
#define NEG     0.2f
#define LN_EPS  1e-5f
#define NBLK    ((N_NODES + 255) / 256)   // 196 scan blocks

typedef __attribute__((ext_vector_type(8))) short short8;
typedef __attribute__((ext_vector_type(4))) float f32x4;

// ---------- fp32 -> bf16 (RNE) split helpers ----------
__device__ __forceinline__ unsigned short f2bf(float f) {
    unsigned u = __float_as_uint(f);
    u += 0x7FFFu + ((u >> 16) & 1u);
    return (unsigned short)(u >> 16);
}
__device__ __forceinline__ float bf2f(unsigned short h) {
    return __uint_as_float(((unsigned)h) << 16);
}

// ========== pack 5 weight matrices into MFMA B-fragment order (hi/lo) ==========
// idx = ((mat*4 + t)*8 + c)*64*8 + l*8 + j ; k = t*32+(l>>4)*8+j ; n = c*16+(l&15)
__global__ __launch_bounds__(256) void pack_w_kernel(
    const float* __restrict__ W0, const float* __restrict__ W1,
    const float* __restrict__ W2, const float* __restrict__ W3,
    const float* __restrict__ W4,
    short* __restrict__ hi, short* __restrict__ lo)
{
    const int idx = blockIdx.x * 256 + threadIdx.x;   // 0..81919
    const int mat = idx >> 14;
    const int rem = idx & 16383;
    const int t = rem >> 12, c = (rem >> 9) & 7, l = (rem >> 3) & 63, j = rem & 7;
    const int k = t * 32 + (l >> 4) * 8 + j;
    const int n = c * 16 + (l & 15);
    const float* W = (mat == 0) ? W0 : (mat == 1) ? W1 : (mat == 2) ? W2
                   : (mat == 3) ? W3 : W4;
    const float v = W[k * DH + n];
    const unsigned short h = f2bf(v);
    hi[idx] = (short)h;
    lo[idx] = (short)f2bf(v - bf2f(h));
}

// ========== split-bf16 MFMA GEMM: Y = A @ W + b, near-fp32 accuracy ==========
// block = 4 waves x 32 rows = 128-row tile; blockIdx.y selects (W,b,Y) set
#define MTILE 128
__global__ __launch_bounds__(256) void gemm_mfma_kernel(
    const float* __restrict__ A, int m_rows,
    const short* __restrict__ Whi0, const short* __restrict__ Wlo0,
    const float* __restrict__ bias0, float* __restrict__ Y0,
    const short* __restrict__ Whi1, const short* __restrict__ Wlo1,
    const float* __restrict__ bias1, float* __restrict__ Y1)
{
    const int w    = threadIdx.x >> 6;
    const int lane = threadIdx.x & 63;
    const short* Whi  = blockIdx.y ? Whi1  : Whi0;
    const short* Wlo  = blockIdx.y ? Wlo1  : Wlo0;
    const float* bias = blockIdx.y ? bias1 : bias0;
    float*       Y    = blockIdx.y ? Y1    : Y0;

    const int rows0 = blockIdx.x * MTILE + w * 32;
    const int g  = lane >> 4;     // k-group
    const int rl = lane & 15;     // row (A) / col (B,C)

    f32x4 acc[2][8];
    #pragma unroll
    for (int r = 0; r < 2; ++r)
        #pragma unroll
        for (int c = 0; c < 8; ++c)
            acc[r][c] = (f32x4){0.f, 0.f, 0.f, 0.f};

    for (int t = 0; t < 4; ++t) {
        short8 ahi[2], alo[2];
        #pragma unroll
        for (int r = 0; r < 2; ++r) {
            int arow = rows0 + 16 * r + rl;
            arow = (arow < m_rows) ? arow : (m_rows - 1);
            const float* ap = A + (size_t)arow * DH + t * 32 + g * 8;
            const float4 f0 = *(const float4*)ap;
            const float4 f1 = *(const float4*)(ap + 4);
            const float fv[8] = {f0.x, f0.y, f0.z, f0.w, f1.x, f1.y, f1.z, f1.w};
            #pragma unroll
            for (int j = 0; j < 8; ++j) {
                const unsigned short h = f2bf(fv[j]);
                ahi[r][j] = (short)h;
                alo[r][j] = (short)f2bf(fv[j] - bf2f(h));
            }
        }
        #pragma unroll
        for (int c = 0; c < 8; ++c) {
            const int fidx = ((t * 8 + c) * 64 + lane) * 8;
            const short8 bhi = *(const short8*)(Whi + fidx);
            const short8 blo = *(const short8*)(Wlo + fidx);
            acc[0][c] = __builtin_amdgcn_mfma_f32_16x16x32_bf16(ahi[0], bhi, acc[0][c], 0, 0, 0);
            acc[1][c] = __builtin_amdgcn_mfma_f32_16x16x32_bf16(ahi[1], bhi, acc[1][c], 0, 0, 0);
            acc[0][c] = __builtin_amdgcn_mfma_f32_16x16x32_bf16(alo[0], bhi, acc[0][c], 0, 0, 0);
            acc[1][c] = __builtin_amdgcn_mfma_f32_16x16x32_bf16(alo[1], bhi, acc[1][c], 0, 0, 0);
            acc[0][c] = __builtin_amdgcn_mfma_f32_16x16x32_bf16(ahi[0], blo, acc[0][c], 0, 0, 0);
            acc[1][c] = __builtin_amdgcn_mfma_f32_16x16x32_bf16(ahi[1], blo, acc[1][c], 0, 0, 0);
        }
    }
    // epilogue: C/D layout col=lane&15, row=(lane>>4)*4+reg
    #pragma unroll
    for (int c = 0; c < 8; ++c) {
        const int col = c * 16 + rl;
        const float bb = bias[col];
        #pragma unroll
        for (int r = 0; r < 2; ++r) {
            #pragma unroll
            for (int q = 0; q < 4; ++q) {
                const int row = rows0 + 16 * r + g * 4 + q;
                if (row < m_rows) Y[(size_t)row * DH + col] = acc[r][c][q] + bb;
            }
        }
    }
}

// ========================= CSR construction =========================
__global__ __launch_bounds__(256) void degree_kernel(
    const int* __restrict__ eidx, int* __restrict__ deg)
{
    const int i = blockIdx.x * 256 + threadIdx.x;
    if (i >= ETOT) return;
    const int d = (i < N_EDGES) ? eidx[N_EDGES + i] : (i - N_EDGES);
    atomicAdd(&deg[d], 1);
}

__global__ __launch_bounds__(256) void block_sum_kernel(
    const int* __restrict__ deg, int* __restrict__ bsum)
{
    const int i    = blockIdx.x * 256 + threadIdx.x;
    const int lane = threadIdx.x & 63;
    const int wid  = threadIdx.x >> 6;
    int v = (i < N_NODES) ? deg[i] : 0;
    #pragma unroll
    for (int off = 32; off; off >>= 1) v += __shfl_xor(v, off);
    __shared__ int ws[4];
    if (lane == 0) ws[wid] = v;
    __syncthreads();
    if (threadIdx.x == 0) bsum[blockIdx.x] = ws[0] + ws[1] + ws[2] + ws[3];
}

__global__ __launch_bounds__(256) void scan_partials_kernel(
    const int* __restrict__ bsum, int* __restrict__ boff)
{
    const int t    = threadIdx.x;
    const int lane = t & 63;
    const int wid  = t >> 6;
    int v = (t < NBLK) ? bsum[t] : 0;
    int inc = v;
    #pragma unroll
    for (int off = 1; off < 64; off <<= 1) {
        int u = __shfl_up(inc, off);
        if (lane >= off) inc += u;
    }
    __shared__ int ws[4];
    if (lane == 63) ws[wid] = inc;
    __syncthreads();
    int add = 0;
    for (int w = 0; w < wid; ++w) add += ws[w];
    if (t < NBLK) boff[t] = add + inc - v;
}

__global__ __launch_bounds__(256) void rowptr_kernel(
    const int* __restrict__ deg, const int* __restrict__ boff,
    int* __restrict__ rowptr, int* __restrict__ cursor)
{
    const int i    = blockIdx.x * 256 + threadIdx.x;
    const int lane = threadIdx.x & 63;
    const int wid  = threadIdx.x >> 6;
    int v = (i < N_NODES) ? deg[i] : 0;
    int inc = v;
    #pragma unroll
    for (int off = 1; off < 64; off <<= 1) {
        int u = __shfl_up(inc, off);
        if (lane >= off) inc += u;
    }
    __shared__ int ws[4];
    if (lane == 63) ws[wid] = inc;
    __syncthreads();
    int add = boff[blockIdx.x];
    for (int w = 0; w < wid; ++w) add += ws[w];
    if (i < N_NODES) {
        const int ex = add + inc - v;
        rowptr[i] = ex;
        cursor[i] = ex;
    }
}

__global__ __launch_bounds__(256) void scatter_kernel(
    const int* __restrict__ eidx, int* __restrict__ cursor,
    int* __restrict__ csr_src)
{
    const int i = blockIdx.x * 256 + threadIdx.x;
    if (i >= ETOT) return;
    int s, d;
    if (i < N_EDGES) { s = eidx[i]; d = eidx[N_EDGES + i]; }
    else             { s = d = i - N_EDGES; }
    const int slot = atomicAdd(&cursor[d], 1);
    csr_src[slot] = s;
}

// ====== fused per-node GAT: 4-way ILP online softmax + bias + LN + GELU ======
__global__ __launch_bounds__(256) void gat_node_kernel(
    const int* __restrict__ rowptr, const int* __restrict__ deg,
    const int* __restrict__ csr_src,
    const float* __restrict__ xl, const float* __restrict__ xr,
    const float* __restrict__ att, const float* __restrict__ bias,
    const float* __restrict__ gam, const float* __restrict__ bet,
    float* __restrict__ out)
{
    const int n    = blockIdx.x * 4 + (threadIdx.x >> 6);
    const int lane = threadIdx.x & 63;
    if (n >= N_NODES) return;
    const int c0 = lane * 2;

    const float2 xrv = *(const float2*)(xr + (size_t)n * DH + c0);
    const float2 atv = *(const float2*)(att + c0);

    float m0 = -INFINITY, m1 = -INFINITY, m2 = -INFINITY, m3 = -INFINITY;
    float d0 = 0.f, d1 = 0.f, d2 = 0.f, d3 = 0.f;
    float p0x = 0.f, p0y = 0.f, p1x = 0.f, p1y = 0.f;
    float p2x = 0.f, p2y = 0.f, p3x = 0.f, p3y = 0.f;

    const int beg = rowptr[n];
    const int end = beg + deg[n];
    int e = beg;

    for (; e + 4 <= end; e += 4) {
        const int s0 = csr_src[e], s1 = csr_src[e+1];
        const int s2 = csr_src[e+2], s3 = csr_src[e+3];
        const float2 x0 = *(const float2*)(xl + (size_t)s0 * DH + c0);
        const float2 x1 = *(const float2*)(xl + (size_t)s1 * DH + c0);
        const float2 x2 = *(const float2*)(xl + (size_t)s2 * DH + c0);
        const float2 x3 = *(const float2*)(xl + (size_t)s3 * DH + c0);

        float t, l0, l1, l2, l3;
        t = x0.x + xrv.x; t = (t > 0.f) ? t : NEG * t; l0  = t * atv.x;
        t = x0.y + xrv.y; t = (t > 0.f) ? t : NEG * t; l0 += t * atv.y;
        t = x1.x + xrv.x; t = (t > 0.f) ? t : NEG * t; l1  = t * atv.x;
        t = x1.y + xrv.y; t = (t > 0.f) ? t : NEG * t; l1 += t * atv.y;
        t = x2.x + xrv.x; t = (t > 0.f) ? t : NEG * t; l2  = t * atv.x;
        t = x2.y + xrv.y; t = (t > 0.f) ? t : NEG * t; l2 += t * atv.y;
        t = x3.x + xrv.x; t = (t > 0.f) ? t : NEG * t; l3  = t * atv.x;
        t = x3.y + xrv.y; t = (t > 0.f) ? t : NEG * t; l3 += t * atv.y;

        l0 += __shfl_xor(l0, 1);  l1 += __shfl_xor(l1, 1);
        l2 += __shfl_xor(l2, 1);  l3 += __shfl_xor(l3, 1);
        l0 += __shfl_xor(l0, 2);  l1 += __shfl_xor(l1, 2);
        l2 += __shfl_xor(l2, 2);  l3 += __shfl_xor(l3, 2);
        l0 += __shfl_xor(l0, 4);  l1 += __shfl_xor(l1, 4);
        l2 += __shfl_xor(l2, 4);  l3 += __shfl_xor(l3, 4);
        l0 += __shfl_xor(l0, 8);  l1 += __shfl_xor(l1, 8);
        l2 += __shfl_xor(l2, 8);  l3 += __shfl_xor(l3, 8);

        float nm, sc, ww;
        nm = fmaxf(m0, l0); sc = __expf(m0 - nm); ww = __expf(l0 - nm);
        d0 = d0 * sc + ww; p0x = p0x * sc + x0.x * ww; p0y = p0y * sc + x0.y * ww; m0 = nm;
        nm = fmaxf(m1, l1); sc = __expf(m1 - nm); ww = __expf(l1 - nm);
        d1 = d1 * sc + ww; p1x = p1x * sc + x1.x * ww; p1y = p1y * sc + x1.y * ww; m1 = nm;
        nm = fmaxf(m2, l2); sc = __expf(m2 - nm); ww = __expf(l2 - nm);
        d2 = d2 * sc + ww; p2x = p2x * sc + x2.x * ww; p2y = p2y * sc + x2.y * ww; m2 = nm;
        nm = fmaxf(m3, l3); sc = __expf(m3 - nm); ww = __expf(l3 - nm);
        d3 = d3 * sc + ww; p3x = p3x * sc + x3.x * ww; p3y = p3y * sc + x3.y * ww; m3 = nm;
    }
    for (; e < end; ++e) {
        const int s = csr_src[e];
        const float2 xv = *(const float2*)(xl + (size_t)s * DH + c0);
        float t, l;
        t = xv.x + xrv.x; t = (t > 0.f) ? t : NEG * t; l  = t * atv.x;
        t = xv.y + xrv.y; t = (t > 0.f) ? t : NEG * t; l += t * atv.y;
        l += __shfl_xor(l, 1);
        l += __shfl_xor(l, 2);
        l += __shfl_xor(l, 4);
        l += __shfl_xor(l, 8);
        const float nm = fmaxf(m0, l);
        const float sc = __expf(m0 - nm);
        const float ww = __expf(l - nm);
        d0 = d0 * sc + ww; p0x = p0x * sc + xv.x * ww; p0y = p0y * sc + xv.y * ww; m0 = nm;
    }

    const float M = fmaxf(fmaxf(m0, m1), fmaxf(m2, m3));
    const float e0 = __expf(m0 - M), e1 = __expf(m1 - M);
    const float e2 = __expf(m2 - M), e3 = __expf(m3 - M);
    const float den = d0*e0 + d1*e1 + d2*e2 + d3*e3;
    const float ax  = p0x*e0 + p1x*e1 + p2x*e2 + p3x*e3;
    const float ay  = p0y*e0 + p1y*e1 + p2y*e2 + p3y*e3;

    const float inv = 1.f / den;
    float v0 = ax * inv + bias[c0];
    float v1 = ay * inv + bias[c0 + 1];

    float s2 = v0 + v1, sq = v0 * v0 + v1 * v1;
    #pragma unroll
    for (int off = 32; off; off >>= 1) {
        s2 += __shfl_xor(s2, off);
        sq += __shfl_xor(sq, off);
    }
    const float mu   = s2 * (1.f / 128.f);
    const float var  = sq * (1.f / 128.f) - mu * mu;
    const float rstd = rsqrtf(var + LN_EPS);

    float y0 = (v0 - mu) * rstd * gam[c0]     + bet[c0];
    float y1 = (v1 - mu) * rstd * gam[c0 + 1] + bet[c0 + 1];
    y0 = 0.5f * y0 * (1.f + erff(y0 * 0.70710678118654752f));
    y1 = 0.5f * y1 * (1.f + erff(y1 * 0.70710678118654752f));

    out[(size_t)n * DH + c0]     = y0;
    out[(size_t)n * DH + c0 + 1] = y1;
}

// ---------- final LayerNorm ----------
__global__ __launch_bounds__(256) void finalize_kernel(
    const float* __restrict__ v_in,
    const float* __restrict__ gam, const float* __restrict__ bet,
    float* __restrict__ out)
{
    const int n    = blockIdx.x * 4 + (threadIdx.x >> 6);
    const int lane = threadIdx.x & 63;
    if (n >= N_NODES) return;
    const int c0 = lane * 2;

    float2 v = *(const float2*)(v_in + (size_t)n * DH + c0);
    float s  = v.x + v.y;
    float sq = v.x * v.x + v.y * v.y;
    #pragma unroll
    for (int off = 32; off; off >>= 1) {
        s  += __shfl_xor(s,  off);
        sq += __shfl_xor(sq, off);
    }
    const float mu   = s  * (1.f / 128.f);
    const float var  = sq * (1.f / 128.f) - mu * mu;
    const float rstd = rsqrtf(var + LN_EPS);

    out[(size_t)n * DH + c0]     = (v.x - mu) * rstd * gam[c0]     + bet[c0];
    out[(size_t)n * DH + c0 + 1] = (v.y - mu) * rstd * gam[c0 + 1] + bet[c0 + 1];
}

extern "C" void kernel_launch(void* const* d_in, const int* in_sizes, int n_in,
                              void* d_out, int out_size, void* d_ws, size_t ws_size,
                              hipStream_t stream)
{
    const float* x    = (const float*)d_in[0];
    const int*   eidx = (const int*)  d_in[1];

    const float* Wl[2]   = { (const float*)d_in[2],  (const float*)d_in[10] };
    const float* bl[2]   = { (const float*)d_in[3],  (const float*)d_in[11] };
    const float* Wr[2]   = { (const float*)d_in[4],  (const float*)d_in[12] };
    const float* br[2]   = { (const float*)d_in[5],  (const float*)d_in[13] };
    const float* att[2]  = { (const float*)d_in[6],  (const float*)d_in[14] };
    const float* bias[2] = { (const float*)d_in[7],  (const float*)d_in[15] };
    const float* gam[2]  = { (const float*)d_in[8],  (const float*)d_in[16] };
    const float* bet[2]  = { (const float*)d_in[9],  (const float*)d_in[17] };
    const float* Wout    = (const float*)d_in[18];
    const float* bout    = (const float*)d_in[19];
    const float* gout    = (const float*)d_in[20];
    const float* boutln  = (const float*)d_in[21];

    float* out = (float*)d_out;

    const size_t NF = (size_t)N_NODES * DH;
    float* xl      = (float*)d_ws;
    float* xr      = xl + NF;
    float* h1      = xr + NF;
    float* h2      = h1 + NF;
    int*   csr_src = (int*)(h2 + NF);
    int*   deg     = csr_src + ETOT;
    int*   rowptr  = deg + N_NODES;
    int*   cursor  = rowptr + N_NODES;
    int*   bsum    = cursor + N_NODES;
    int*   boff    = bsum + NBLK;
    short* whi     = (short*)(boff + NBLK);   // 5 * 16384 shorts
    short* wlo     = whi + 5 * 16384;

    const int etBlocks   = (ETOT + 255) / 256;
    const int nodeBlocks = N_NODES / 4;
    const int gemmBlocks = (N_NODES + MTILE - 1) / MTILE;   // 391

    // per-matrix packed offsets: 0=Wl0 1=Wr0 2=Wl1 3=Wr1 4=Wout
    #define WP(i) (whi + (i) * 16384), (wlo + (i) * 16384)

    // ---- CSR (deterministic rebuild every call) ----
    hipMemsetAsync(deg, 0, N_NODES * sizeof(int), stream);
    degree_kernel       <<<etBlocks, 256, 0, stream>>>(eidx, deg);
    block_sum_kernel    <<<NBLK, 256, 0, stream>>>(deg, bsum);
    scan_partials_kernel<<<1, 256, 0, stream>>>(bsum, boff);
    rowptr_kernel       <<<NBLK, 256, 0, stream>>>(deg, boff, rowptr, cursor);
    scatter_kernel      <<<etBlocks, 256, 0, stream>>>(eidx, cursor, csr_src);

    // ---- pack all 5 weight matrices ----
    pack_w_kernel<<<320, 256, 0, stream>>>(Wl[0], Wr[0], Wl[1], Wr[1], Wout, whi, wlo);

    // ---- layer 0 ----
    gemm_mfma_kernel<<<dim3(gemmBlocks, 2), 256, 0, stream>>>(
        x, N_NODES, WP(0), bl[0], xl, WP(1), br[0], xr);
    gat_node_kernel<<<nodeBlocks, 256, 0, stream>>>(rowptr, deg, csr_src, xl, xr,
                                                    att[0], bias[0], gam[0], bet[0], h1);
    // ---- layer 1 ----
    gemm_mfma_kernel<<<dim3(gemmBlocks, 2), 256, 0, stream>>>(
        h1, N_NODES, WP(2), bl[1], xl, WP(3), br[1], xr);
    gat_node_kernel<<<nodeBlocks, 256, 0, stream>>>(rowptr, deg, csr_src, xl, xr,
                                                    att[1], bias[1], gam[1], bet[1], h2);

    // ---- output projection + final LayerNorm ----
    gemm_mfma_kernel<<<dim3(gemmBlocks, 1), 256, 0, stream>>>(
        h2, N_NODES, WP(4), bout, xl, WP(4), bout, xl);
    finalize_kernel<<<nodeBlocks, 256, 0, stream>>>(xl, gout, boutln, out);
}

// Round 5
// 351.881 us; speedup vs baseline: 9.7102x; 1.0069x over previous
//
#include <hip/hip_runtime.h>
#include <math.h>

#define N_NODES 50000
#define N_EDGES 800000
#define ETOT    (N_EDGES + N_NODES)
#define DH      128
#define NH      4
#define NEG     0.2f
#define LN_EPS  1e-5f
#define NBLK    ((N_NODES + 255) / 256)   // 196 scan blocks

typedef __attribute__((ext_vector_type(8))) short short8;
typedef __attribute__((ext_vector_type(4))) float f32x4;

// ---------- fp32 -> bf16 (RNE) split helpers ----------
__device__ __forceinline__ unsigned short f2bf(float f) {
    unsigned u = __float_as_uint(f);
    u += 0x7FFFu + ((u >> 16) & 1u);
    return (unsigned short)(u >> 16);
}
__device__ __forceinline__ float bf2f(unsigned short h) {
    return __uint_as_float(((unsigned)h) << 16);
}

// ========== pack 5 weight matrices into MFMA B-fragment order (hi/lo) ==========
__global__ __launch_bounds__(256) void pack_w_kernel(
    const float* __restrict__ W0, const float* __restrict__ W1,
    const float* __restrict__ W2, const float* __restrict__ W3,
    const float* __restrict__ W4,
    short* __restrict__ hi, short* __restrict__ lo)
{
    const int idx = blockIdx.x * 256 + threadIdx.x;   // 0..81919
    const int mat = idx >> 14;
    const int rem = idx & 16383;
    const int t = rem >> 12, c = (rem >> 9) & 7, l = (rem >> 3) & 63, j = rem & 7;
    const int k = t * 32 + (l >> 4) * 8 + j;
    const int n = c * 16 + (l & 15);
    const float* W = (mat == 0) ? W0 : (mat == 1) ? W1 : (mat == 2) ? W2
                   : (mat == 3) ? W3 : W4;
    const float v = W[k * DH + n];
    const unsigned short h = f2bf(v);
    hi[idx] = (short)h;
    lo[idx] = (short)f2bf(v - bf2f(h));
}

// ========== split-bf16 MFMA GEMM: Y = A @ W + b ==========
#define MTILE 128
__global__ __launch_bounds__(256) void gemm_mfma_kernel(
    const float* __restrict__ A, int m_rows,
    const short* __restrict__ Whi0, const short* __restrict__ Wlo0,
    const float* __restrict__ bias0, float* __restrict__ Y0,
    const short* __restrict__ Whi1, const short* __restrict__ Wlo1,
    const float* __restrict__ bias1, float* __restrict__ Y1)
{
    const int w    = threadIdx.x >> 6;
    const int lane = threadIdx.x & 63;
    const short* Whi  = blockIdx.y ? Whi1  : Whi0;
    const short* Wlo  = blockIdx.y ? Wlo1  : Wlo0;
    const float* bias = blockIdx.y ? bias1 : bias0;
    float*       Y    = blockIdx.y ? Y1    : Y0;

    const int rows0 = blockIdx.x * MTILE + w * 32;
    const int g  = lane >> 4;
    const int rl = lane & 15;

    f32x4 acc[2][8];
    #pragma unroll
    for (int r = 0; r < 2; ++r)
        #pragma unroll
        for (int c = 0; c < 8; ++c)
            acc[r][c] = (f32x4){0.f, 0.f, 0.f, 0.f};

    for (int t = 0; t < 4; ++t) {
        short8 ahi[2], alo[2];
        #pragma unroll
        for (int r = 0; r < 2; ++r) {
            int arow = rows0 + 16 * r + rl;
            arow = (arow < m_rows) ? arow : (m_rows - 1);
            const float* ap = A + (size_t)arow * DH + t * 32 + g * 8;
            const float4 f0 = *(const float4*)ap;
            const float4 f1 = *(const float4*)(ap + 4);
            const float fv[8] = {f0.x, f0.y, f0.z, f0.w, f1.x, f1.y, f1.z, f1.w};
            #pragma unroll
            for (int j = 0; j < 8; ++j) {
                const unsigned short h = f2bf(fv[j]);
                ahi[r][j] = (short)h;
                alo[r][j] = (short)f2bf(fv[j] - bf2f(h));
            }
        }
        #pragma unroll
        for (int c = 0; c < 8; ++c) {
            const int fidx = ((t * 8 + c) * 64 + lane) * 8;
            const short8 bhi = *(const short8*)(Whi + fidx);
            const short8 blo = *(const short8*)(Wlo + fidx);
            acc[0][c] = __builtin_amdgcn_mfma_f32_16x16x32_bf16(ahi[0], bhi, acc[0][c], 0, 0, 0);
            acc[1][c] = __builtin_amdgcn_mfma_f32_16x16x32_bf16(ahi[1], bhi, acc[1][c], 0, 0, 0);
            acc[0][c] = __builtin_amdgcn_mfma_f32_16x16x32_bf16(alo[0], bhi, acc[0][c], 0, 0, 0);
            acc[1][c] = __builtin_amdgcn_mfma_f32_16x16x32_bf16(alo[1], bhi, acc[1][c], 0, 0, 0);
            acc[0][c] = __builtin_amdgcn_mfma_f32_16x16x32_bf16(ahi[0], blo, acc[0][c], 0, 0, 0);
            acc[1][c] = __builtin_amdgcn_mfma_f32_16x16x32_bf16(ahi[1], blo, acc[1][c], 0, 0, 0);
        }
    }
    #pragma unroll
    for (int c = 0; c < 8; ++c) {
        const int col = c * 16 + rl;
        const float bb = bias[col];
        #pragma unroll
        for (int r = 0; r < 2; ++r) {
            #pragma unroll
            for (int q = 0; q < 4; ++q) {
                const int row = rows0 + 16 * r + g * 4 + q;
                if (row < m_rows) Y[(size_t)row * DH + col] = acc[r][c][q] + bb;
            }
        }
    }
}

// ========================= CSR construction =========================
__global__ __launch_bounds__(256) void degree_kernel(
    const int* __restrict__ eidx, int* __restrict__ deg)
{
    const int i = blockIdx.x * 256 + threadIdx.x;
    if (i >= ETOT) return;
    const int d = (i < N_EDGES) ? eidx[N_EDGES + i] : (i - N_EDGES);
    atomicAdd(&deg[d], 1);
}

__global__ __launch_bounds__(256) void block_sum_kernel(
    const int* __restrict__ deg, int* __restrict__ bsum)
{
    const int i    = blockIdx.x * 256 + threadIdx.x;
    const int lane = threadIdx.x & 63;
    const int wid  = threadIdx.x >> 6;
    int v = (i < N_NODES) ? deg[i] : 0;
    #pragma unroll
    for (int off = 32; off; off >>= 1) v += __shfl_xor(v, off);
    __shared__ int ws[4];
    if (lane == 0) ws[wid] = v;
    __syncthreads();
    if (threadIdx.x == 0) bsum[blockIdx.x] = ws[0] + ws[1] + ws[2] + ws[3];
}

__global__ __launch_bounds__(256) void scan_partials_kernel(
    const int* __restrict__ bsum, int* __restrict__ boff)
{
    const int t    = threadIdx.x;
    const int lane = t & 63;
    const int wid  = t >> 6;
    int v = (t < NBLK) ? bsum[t] : 0;
    int inc = v;
    #pragma unroll
    for (int off = 1; off < 64; off <<= 1) {
        int u = __shfl_up(inc, off);
        if (lane >= off) inc += u;
    }
    __shared__ int ws[4];
    if (lane == 63) ws[wid] = inc;
    __syncthreads();
    int add = 0;
    for (int w = 0; w < wid; ++w) add += ws[w];
    if (t < NBLK) boff[t] = add + inc - v;
}

__global__ __launch_bounds__(256) void rowptr_kernel(
    const int* __restrict__ deg, const int* __restrict__ boff,
    int* __restrict__ rowptr, int* __restrict__ cursor)
{
    const int i    = blockIdx.x * 256 + threadIdx.x;
    const int lane = threadIdx.x & 63;
    const int wid  = threadIdx.x >> 6;
    int v = (i < N_NODES) ? deg[i] : 0;
    int inc = v;
    #pragma unroll
    for (int off = 1; off < 64; off <<= 1) {
        int u = __shfl_up(inc, off);
        if (lane >= off) inc += u;
    }
    __shared__ int ws[4];
    if (lane == 63) ws[wid] = inc;
    __syncthreads();
    int add = boff[blockIdx.x];
    for (int w = 0; w < wid; ++w) add += ws[w];
    if (i < N_NODES) {
        const int ex = add + inc - v;
        rowptr[i] = ex;
        cursor[i] = ex;
    }
}

__global__ __launch_bounds__(256) void scatter_kernel(
    const int* __restrict__ eidx, int* __restrict__ cursor,
    int* __restrict__ csr_src)
{
    const int i = blockIdx.x * 256 + threadIdx.x;
    if (i >= ETOT) return;
    int s, d;
    if (i < N_EDGES) { s = eidx[i]; d = eidx[N_EDGES + i]; }
    else             { s = d = i - N_EDGES; }
    const int slot = atomicAdd(&cursor[d], 1);
    csr_src[slot] = s;
}

// ====== fused per-node GAT: 2 edges/wave (32 lanes, 4 ch each), base-2 softmax ======
// wave = one dst node; half = lane>>5 picks the edge slot; 8-lane head groups
__global__ __launch_bounds__(256) void gat_node_kernel(
    const int* __restrict__ rowptr, const int* __restrict__ deg,
    const int* __restrict__ csr_src,
    const float* __restrict__ xl, const float* __restrict__ xr,
    const float* __restrict__ att, const float* __restrict__ bias,
    const float* __restrict__ gam, const float* __restrict__ bet,
    float* __restrict__ out)
{
    const int n    = blockIdx.x * 4 + (threadIdx.x >> 6);
    const int lane = threadIdx.x & 63;
    if (n >= N_NODES) return;
    const int half = lane >> 5;
    const int cl   = lane & 31;
    const int c0   = cl * 4;

    const float4 xrv = *(const float4*)(xr + (size_t)n * DH + c0);
    float4 atv = *(const float4*)(att + c0);
    const float LOG2E = 1.4426950408889634f;
    atv.x *= LOG2E; atv.y *= LOG2E; atv.z *= LOG2E; atv.w *= LOG2E;

    // two independent online-softmax states (base-2 exponent domain)
    float m0 = -INFINITY, d0 = 0.f;
    float4 p0 = {0.f, 0.f, 0.f, 0.f};
    float m1 = -INFINITY, d1 = 0.f;
    float4 p1 = {0.f, 0.f, 0.f, 0.f};

    const int beg = rowptr[n];
    const int end = beg + deg[n];
    int e = beg;

    // main loop: 4 edges per iter; this lane's edges: e+2*half, e+2*half+1
    for (; e + 4 <= end; e += 4) {
        const int eb = e + 2 * half;
        const int s0 = csr_src[eb];
        const int s1 = csr_src[eb + 1];
        const float4 x0 = *(const float4*)(xl + (size_t)s0 * DH + c0);
        const float4 x1 = *(const float4*)(xl + (size_t)s1 * DH + c0);

        float t, l0, l1;
        t = x0.x + xrv.x; t = fmaxf(t, NEG * t); l0  = t * atv.x;
        t = x0.y + xrv.y; t = fmaxf(t, NEG * t); l0 += t * atv.y;
        t = x0.z + xrv.z; t = fmaxf(t, NEG * t); l0 += t * atv.z;
        t = x0.w + xrv.w; t = fmaxf(t, NEG * t); l0 += t * atv.w;
        t = x1.x + xrv.x; t = fmaxf(t, NEG * t); l1  = t * atv.x;
        t = x1.y + xrv.y; t = fmaxf(t, NEG * t); l1 += t * atv.y;
        t = x1.z + xrv.z; t = fmaxf(t, NEG * t); l1 += t * atv.z;
        t = x1.w + xrv.w; t = fmaxf(t, NEG * t); l1 += t * atv.w;

        // head reduce: 8 lanes per head (stays within half and head group)
        l0 += __shfl_xor(l0, 1);  l1 += __shfl_xor(l1, 1);
        l0 += __shfl_xor(l0, 2);  l1 += __shfl_xor(l1, 2);
        l0 += __shfl_xor(l0, 4);  l1 += __shfl_xor(l1, 4);

        float nm, sc, w;
        nm = fmaxf(m0, l0); sc = exp2f(m0 - nm); w = exp2f(l0 - nm);
        d0 = d0 * sc + w;
        p0.x = p0.x * sc + x0.x * w;  p0.y = p0.y * sc + x0.y * w;
        p0.z = p0.z * sc + x0.z * w;  p0.w = p0.w * sc + x0.w * w;
        m0 = nm;
        nm = fmaxf(m1, l1); sc = exp2f(m1 - nm); w = exp2f(l1 - nm);
        d1 = d1 * sc + w;
        p1.x = p1.x * sc + x1.x * w;  p1.y = p1.y * sc + x1.y * w;
        p1.z = p1.z * sc + x1.z * w;  p1.w = p1.w * sc + x1.w * w;
        m1 = nm;
    }

    // tail: up to 3 edges, 2 per iter with masking -> state 0
    for (; e < end; e += 2) {
        const int ei    = e + half;
        const bool valid = (ei < end);
        const int s = csr_src[valid ? ei : beg];
        const float4 xv = *(const float4*)(xl + (size_t)s * DH + c0);

        float t, l;
        t = xv.x + xrv.x; t = fmaxf(t, NEG * t); l  = t * atv.x;
        t = xv.y + xrv.y; t = fmaxf(t, NEG * t); l += t * atv.y;
        t = xv.z + xrv.z; t = fmaxf(t, NEG * t); l += t * atv.z;
        t = xv.w + xrv.w; t = fmaxf(t, NEG * t); l += t * atv.w;
        l += __shfl_xor(l, 1);
        l += __shfl_xor(l, 2);
        l += __shfl_xor(l, 4);

        float nm = fmaxf(m0, l);
        float sc = exp2f(m0 - nm);
        float w  = exp2f(l - nm);
        if (!valid) { nm = m0; sc = 1.f; w = 0.f; }   // avoid -inf - -inf NaN
        d0 = d0 * sc + w;
        p0.x = p0.x * sc + xv.x * w;  p0.y = p0.y * sc + xv.y * w;
        p0.z = p0.z * sc + xv.z * w;  p0.w = p0.w * sc + xv.w * w;
        m0 = nm;
    }

    // merge state1 into state0 (guarded: either m may be -inf)
    {
        const float M  = fmaxf(m0, m1);
        const float ea = (m0 == M) ? 1.f : exp2f(m0 - M);
        const float eb = (m1 == M) ? 1.f : exp2f(m1 - M);
        d0  = d0 * ea + d1 * eb;
        p0.x = p0.x * ea + p1.x * eb;  p0.y = p0.y * ea + p1.y * eb;
        p0.z = p0.z * ea + p1.z * eb;  p0.w = p0.w * ea + p1.w * eb;
        m0 = M;
    }
    // cross-half merge (lane ^ 32); both halves end with identical state
    {
        const float mo = __shfl_xor(m0, 32);
        const float dd = __shfl_xor(d0, 32);
        const float qx = __shfl_xor(p0.x, 32), qy = __shfl_xor(p0.y, 32);
        const float qz = __shfl_xor(p0.z, 32), qw = __shfl_xor(p0.w, 32);
        const float M  = fmaxf(m0, mo);
        const float ea = (m0 == M) ? 1.f : exp2f(m0 - M);
        const float eb = (mo == M) ? 1.f : exp2f(mo - M);
        d0  = d0 * ea + dd * eb;
        p0.x = p0.x * ea + qx * eb;  p0.y = p0.y * ea + qy * eb;
        p0.z = p0.z * ea + qz * eb;  p0.w = p0.w * ea + qw * eb;
    }

    const float inv = 1.f / d0;
    const float4 bi = *(const float4*)(bias + c0);
    float v0 = p0.x * inv + bi.x;
    float v1 = p0.y * inv + bi.y;
    float v2 = p0.z * inv + bi.z;
    float v3 = p0.w * inv + bi.w;

    // LayerNorm over 128 ch = 32 lanes x 4 (xor 1..16 stays within half)
    float s2 = v0 + v1 + v2 + v3;
    float sq = v0*v0 + v1*v1 + v2*v2 + v3*v3;
    #pragma unroll
    for (int off = 16; off; off >>= 1) {
        s2 += __shfl_xor(s2, off);
        sq += __shfl_xor(sq, off);
    }
    const float mu   = s2 * (1.f / 128.f);
    const float var  = sq * (1.f / 128.f) - mu * mu;
    const float rstd = rsqrtf(var + LN_EPS);

    const float4 gm = *(const float4*)(gam + c0);
    const float4 bt = *(const float4*)(bet + c0);
    float y0 = (v0 - mu) * rstd * gm.x + bt.x;
    float y1 = (v1 - mu) * rstd * gm.y + bt.y;
    float y2 = (v2 - mu) * rstd * gm.z + bt.z;
    float y3 = (v3 - mu) * rstd * gm.w + bt.w;
    y0 = 0.5f * y0 * (1.f + erff(y0 * 0.70710678118654752f));
    y1 = 0.5f * y1 * (1.f + erff(y1 * 0.70710678118654752f));
    y2 = 0.5f * y2 * (1.f + erff(y2 * 0.70710678118654752f));
    y3 = 0.5f * y3 * (1.f + erff(y3 * 0.70710678118654752f));

    if (half == 0) {
        float4 yv = {y0, y1, y2, y3};
        *(float4*)(out + (size_t)n * DH + c0) = yv;
    }
}

// ---------- final LayerNorm ----------
__global__ __launch_bounds__(256) void finalize_kernel(
    const float* __restrict__ v_in,
    const float* __restrict__ gam, const float* __restrict__ bet,
    float* __restrict__ out)
{
    const int n    = blockIdx.x * 4 + (threadIdx.x >> 6);
    const int lane = threadIdx.x & 63;
    if (n >= N_NODES) return;
    const int c0 = lane * 2;

    float2 v = *(const float2*)(v_in + (size_t)n * DH + c0);
    float s  = v.x + v.y;
    float sq = v.x * v.x + v.y * v.y;
    #pragma unroll
    for (int off = 32; off; off >>= 1) {
        s  += __shfl_xor(s,  off);
        sq += __shfl_xor(sq, off);
    }
    const float mu   = s  * (1.f / 128.f);
    const float var  = sq * (1.f / 128.f) - mu * mu;
    const float rstd = rsqrtf(var + LN_EPS);

    out[(size_t)n * DH + c0]     = (v.x - mu) * rstd * gam[c0]     + bet[c0];
    out[(size_t)n * DH + c0 + 1] = (v.y - mu) * rstd * gam[c0 + 1] + bet[c0 + 1];
}

extern "C" void kernel_launch(void* const* d_in, const int* in_sizes, int n_in,
                              void* d_out, int out_size, void* d_ws, size_t ws_size,
                              hipStream_t stream)
{
    const float* x    = (const float*)d_in[0];
    const int*   eidx = (const int*)  d_in[1];

    const float* Wl[2]   = { (const float*)d_in[2],  (const float*)d_in[10] };
    const float* bl[2]   = { (const float*)d_in[3],  (const float*)d_in[11] };
    const float* Wr[2]   = { (const float*)d_in[4],  (const float*)d_in[12] };
    const float* br[2]   = { (const float*)d_in[5],  (const float*)d_in[13] };
    const float* att[2]  = { (const float*)d_in[6],  (const float*)d_in[14] };
    const float* bias[2] = { (const float*)d_in[7],  (const float*)d_in[15] };
    const float* gam[2]  = { (const float*)d_in[8],  (const float*)d_in[16] };
    const float* bet[2]  = { (const float*)d_in[9],  (const float*)d_in[17] };
    const float* Wout    = (const float*)d_in[18];
    const float* bout    = (const float*)d_in[19];
    const float* gout    = (const float*)d_in[20];
    const float* boutln  = (const float*)d_in[21];

    float* out = (float*)d_out;

    const size_t NF = (size_t)N_NODES * DH;
    float* xl      = (float*)d_ws;
    float* xr      = xl + NF;
    float* h1      = xr + NF;
    float* h2      = h1 + NF;
    int*   csr_src = (int*)(h2 + NF);
    int*   deg     = csr_src + ETOT;
    int*   rowptr  = deg + N_NODES;
    int*   cursor  = rowptr + N_NODES;
    int*   bsum    = cursor + N_NODES;
    int*   boff    = bsum + NBLK;
    short* whi     = (short*)(boff + NBLK);   // 5 * 16384 shorts
    short* wlo     = whi + 5 * 16384;

    const int etBlocks   = (ETOT + 255) / 256;
    const int nodeBlocks = N_NODES / 4;
    const int gemmBlocks = (N_NODES + MTILE - 1) / MTILE;   // 391

    #define WP(i) (whi + (i) * 16384), (wlo + (i) * 16384)

    // ---- CSR (deterministic rebuild every call) ----
    hipMemsetAsync(deg, 0, N_NODES * sizeof(int), stream);
    degree_kernel       <<<etBlocks, 256, 0, stream>>>(eidx, deg);
    block_sum_kernel    <<<NBLK, 256, 0, stream>>>(deg, bsum);
    scan_partials_kernel<<<1, 256, 0, stream>>>(bsum, boff);
    rowptr_kernel       <<<NBLK, 256, 0, stream>>>(deg, boff, rowptr, cursor);
    scatter_kernel      <<<etBlocks, 256, 0, stream>>>(eidx, cursor, csr_src);

    // ---- pack all 5 weight matrices ----
    pack_w_kernel<<<320, 256, 0, stream>>>(Wl[0], Wr[0], Wl[1], Wr[1], Wout, whi, wlo);

    // ---- layer 0 ----
    gemm_mfma_kernel<<<dim3(gemmBlocks, 2), 256, 0, stream>>>(
        x, N_NODES, WP(0), bl[0], xl, WP(1), br[0], xr);
    gat_node_kernel<<<nodeBlocks, 256, 0, stream>>>(rowptr, deg, csr_src, xl, xr,
                                                    att[0], bias[0], gam[0], bet[0], h1);
    // ---- layer 1 ----
    gemm_mfma_kernel<<<dim3(gemmBlocks, 2), 256, 0, stream>>>(
        h1, N_NODES, WP(2), bl[1], xl, WP(3), br[1], xr);
    gat_node_kernel<<<nodeBlocks, 256, 0, stream>>>(rowptr, deg, csr_src, xl, xr,
                                                    att[1], bias[1], gam[1], bet[1], h2);

    // ---- output projection + final LayerNorm ----
    gemm_mfma_kernel<<<dim3(gemmBlocks, 1), 256, 0, stream>>>(
        h2, N_NODES, WP(4), bout, xl, WP(4), bout, xl);
    finalize_kernel<<<nodeBlocks, 256, 0, stream>>>(xl, gout, boutln, out);
}